// Round 5
// baseline (491.801 us; speedup 1.0000x reference)
//
#include <hip/hip_runtime.h>
#include <hip/hip_bf16.h>

#define N_NODES 50000
#define IN_C    96
#define HID_C   128
#define OUT_C   64
#define MROWS   50016 // 32-row-tile padded M

// CSR-build partition params
#define NB      200   // coarse buckets
#define BSZ     250   // nodes per bucket (200*250 = 50000)
#define WCHUNK  4096  // edges per workgroup in partition passes
#define NWG     196   // ceil(800000/4096)

typedef __attribute__((ext_vector_type(8))) short short8;  // 8 bf16 (4 VGPR)
typedef __attribute__((ext_vector_type(4))) float f32x4;

// round-to-nearest-even fp32 -> bf16 bits
__device__ inline unsigned int f2bf(float f) {
    unsigned int u = __float_as_uint(f);
    return (u + 0x7fffu + ((u >> 16) & 1u)) >> 16;
}
__device__ inline unsigned int pack2(float lo, float hi) {
    return f2bf(lo) | (f2bf(hi) << 16);
}
__device__ inline float blo(unsigned int u) { return __uint_as_float(u << 16); }
__device__ inline float bhi(unsigned int u) { return __uint_as_float(u & 0xffff0000u); }

// ---------------------------------------------------------------------------
// P1: per-WG coarse histogram (LDS, no global atomics).
// ---------------------------------------------------------------------------
__global__ __launch_bounds__(256) void parta_hist(
    const int* __restrict__ dst, int* __restrict__ gh, int E)
{
    __shared__ int h[NB];
    int t = threadIdx.x;
    if (t < NB) h[t] = 0;
    __syncthreads();
    int base_e = blockIdx.x * WCHUNK;
    for (int i = t; i < WCHUNK; i += 256) {
        int e = base_e + i;
        if (e < E) atomicAdd(&h[dst[e] / BSZ], 1);
    }
    __syncthreads();
    if (t < NB) gh[blockIdx.x * NB + t] = h[t];
}

// ---------------------------------------------------------------------------
// P2: bucket bases (exclusive scan of totals) + per-(WG,bucket) offsets.
// ---------------------------------------------------------------------------
__global__ __launch_bounds__(256) void parta_scan(
    const int* __restrict__ gh, int* __restrict__ ofs,
    int* __restrict__ base)
{
    __shared__ int buf[256];
    int t = threadIdx.x;
    int tot = 0;
    if (t < NB) {
        for (int w = 0; w < NWG; w++) tot += gh[w * NB + t];
    }
    buf[t] = tot;
    __syncthreads();
    for (int off = 1; off < 256; off <<= 1) {       // inclusive scan
        int v = (t >= off) ? buf[t - off] : 0;
        __syncthreads();
        buf[t] += v;
        __syncthreads();
    }
    if (t < NB) {
        int excl = buf[t] - tot;
        base[t] = excl;
        if (t == NB - 1) base[NB] = excl + tot;     // == E
        int run = excl;
        for (int w = 0; w < NWG; w++) {
            ofs[w * NB + t] = run;
            run += gh[w * NB + t];
        }
    }
}

// ---------------------------------------------------------------------------
// P3: partition edges into bucket-ordered packed records:
// rec = src (16b) | bucket-local dst (8b) << 16.  4 B/edge.
// ---------------------------------------------------------------------------
__global__ __launch_bounds__(256) void parta_scatter(
    const int* __restrict__ src, const int* __restrict__ dst,
    const int* __restrict__ ofs, unsigned int* __restrict__ pairs, int E)
{
    __shared__ int cur[NB];
    int t = threadIdx.x;
    if (t < NB) cur[t] = ofs[blockIdx.x * NB + t];
    __syncthreads();
    int base_e = blockIdx.x * WCHUNK;
    for (int i = t; i < WCHUNK; i += 256) {
        int e = base_e + i;
        if (e < E) {
            int d = dst[e];
            int b = d / BSZ;
            int pos = atomicAdd(&cur[b], 1);
            pairs[pos] = (unsigned)src[e] | ((unsigned)(d - b * BSZ) << 16);
        }
    }
}

// ---------------------------------------------------------------------------
// P4: per-bucket fine CSR (LDS hist + scan + rank); adj as ushort (src<65536).
// ---------------------------------------------------------------------------
__global__ __launch_bounds__(256) void partb_csr(
    const unsigned int* __restrict__ pairs, const int* __restrict__ base,
    int* __restrict__ rowstart, int* __restrict__ cnt,
    unsigned short* __restrict__ adj)
{
    __shared__ int h[256];
    __shared__ int buf[256];
    __shared__ int cur[256];
    int b = blockIdx.x;
    int t = threadIdx.x;
    int beg = base[b], end = base[b + 1];
    int node0 = b * BSZ;
    h[t] = 0;
    __syncthreads();
    for (int i = beg + t; i < end; i += 256)
        atomicAdd(&h[pairs[i] >> 16], 1);
    __syncthreads();
    int c = h[t];
    buf[t] = c;
    __syncthreads();
    for (int off = 1; off < 256; off <<= 1) {       // inclusive scan
        int v = (t >= off) ? buf[t - off] : 0;
        __syncthreads();
        buf[t] += v;
        __syncthreads();
    }
    int excl = buf[t] - c;
    if (t < BSZ) {
        rowstart[node0 + t] = beg + excl;
        cnt[node0 + t] = c;
    }
    cur[t] = beg + excl;
    __syncthreads();
    for (int i = beg + t; i < end; i += 256) {
        unsigned int pr = pairs[i];
        int pos = atomicAdd(&cur[pr >> 16], 1);
        adj[pos] = (unsigned short)(pr & 0xffffu);
    }
}

// ---------------------------------------------------------------------------
// Degree-sort: counting sort of nodes by in-degree -> perm[] so that
// consecutive gather threads handle equal-degree nodes (no wave divergence).
// ---------------------------------------------------------------------------
__global__ __launch_bounds__(256) void deg_hist(
    const int* __restrict__ cnt, int* __restrict__ dh)
{
    int n = blockIdx.x * 256 + threadIdx.x;
    if (n < N_NODES) atomicAdd(&dh[min(cnt[n], 255)], 1);
}

__global__ __launch_bounds__(256) void deg_scan(
    const int* __restrict__ dh, int* __restrict__ dcur)
{
    __shared__ int buf[256];
    int t = threadIdx.x;
    int v0 = dh[t];
    buf[t] = v0;
    __syncthreads();
    for (int off = 1; off < 256; off <<= 1) {
        int v = (t >= off) ? buf[t - off] : 0;
        __syncthreads();
        buf[t] += v;
        __syncthreads();
    }
    dcur[t] = buf[t] - v0;                           // exclusive
}

__global__ __launch_bounds__(256) void deg_fill(
    const int* __restrict__ cnt, int* __restrict__ dcur,
    int* __restrict__ perm)
{
    int n = blockIdx.x * 256 + threadIdx.x;
    if (n < N_NODES) {
        int pos = atomicAdd(&dcur[min(cnt[n], 255)], 1);
        perm[pos] = n;
    }
}

// ---------------------------------------------------------------------------
// Converters (fp32 -> bf16)
// ---------------------------------------------------------------------------
__global__ __launch_bounds__(256) void conv_x_kernel(
    const float* __restrict__ x, uint4* __restrict__ xb4,
    uint4* __restrict__ a14)
{
    int idx = blockIdx.x * 256 + threadIdx.x;     // N*12
    if (idx >= N_NODES * 12) return;
    int node = idx / 12;
    int c = idx - node * 12;
    const float4* x4 = (const float4*)x;
    float4 u = x4[(size_t)node * 24 + 2 * c];
    float4 v = x4[(size_t)node * 24 + 2 * c + 1];
    uint4 w;
    w.x = pack2(u.x, u.y); w.y = pack2(u.z, u.w);
    w.z = pack2(v.x, v.y); w.w = pack2(v.z, v.w);
    xb4[(size_t)node * 12 + c] = w;
    a14[(size_t)node * 24 + 12 + c] = w;
}

// Fused weight convert: W1t[128][192] and W2t[128][128].
__global__ __launch_bounds__(256) void conv_w_kernel(
    const float* __restrict__ w1l, const float* __restrict__ w1r,
    const float* __restrict__ w2l, const float* __restrict__ w2r,
    unsigned short* __restrict__ wt1, unsigned short* __restrict__ wt2)
{
    int i = blockIdx.x * 256 + threadIdx.x;
    if (i < 128 * 192) {
        int col = i / 192, k = i - col * 192;
        float v = (k < 96) ? w1l[k * 128 + col] : w1r[(k - 96) * 128 + col];
        wt1[i] = (unsigned short)f2bf(v);
    } else {
        int j = i - 128 * 192;
        if (j < 128 * 128) {
            int col = j / 128, k = j - col * 128;
            float v = (col < 64) ? w2l[k * 64 + col] : w2r[k * 64 + col - 64];
            wt2[j] = (unsigned short)f2bf(v);
        }
    }
}

// ---------------------------------------------------------------------------
// Gather 1: A1[n][0..95] = (sum_{j in N(n)} xb[j]) / deg(n), bf16 out.
// thread = (perm-pos, 32B chunk c in 0..5); 2 independent uint4 loads/edge.
// ---------------------------------------------------------------------------
__global__ __launch_bounds__(256) void gather1_kernel(
    const int* __restrict__ perm, const int* __restrict__ rowstart,
    const int* __restrict__ cnt, const unsigned short* __restrict__ adj,
    const uint4* __restrict__ xb4, uint4* __restrict__ a14)
{
    int idx = blockIdx.x * 256 + threadIdx.x;
    if (idx >= N_NODES * 6) return;
    int i = idx / 6;
    int c = idx - i * 6;
    int node = perm[i];
    int beg = rowstart[node];
    int d = cnt[node];
    int end = beg + d;
    float a0=0,a1=0,a2=0,a3=0,a4=0,a5=0,a6=0,a7=0;
    float b0=0,b1=0,b2=0,b3=0,b4=0,b5=0,b6=0,b7=0;
    for (int j = beg; j < end; j++) {
        int s = adj[j];
        uint4 u = xb4[(size_t)s * 12 + 2 * c];
        uint4 v = xb4[(size_t)s * 12 + 2 * c + 1];
        a0 += blo(u.x); a1 += bhi(u.x); a2 += blo(u.y); a3 += bhi(u.y);
        a4 += blo(u.z); a5 += bhi(u.z); a6 += blo(u.w); a7 += bhi(u.w);
        b0 += blo(v.x); b1 += bhi(v.x); b2 += blo(v.y); b3 += bhi(v.y);
        b4 += blo(v.z); b5 += bhi(v.z); b6 += blo(v.w); b7 += bhi(v.w);
    }
    float id = 1.0f / (float)max(d, 1);
    uint4 w0, w1;
    w0.x = pack2(a0 * id, a1 * id); w0.y = pack2(a2 * id, a3 * id);
    w0.z = pack2(a4 * id, a5 * id); w0.w = pack2(a6 * id, a7 * id);
    w1.x = pack2(b0 * id, b1 * id); w1.y = pack2(b2 * id, b3 * id);
    w1.z = pack2(b4 * id, b5 * id); w1.w = pack2(b6 * id, b7 * id);
    a14[(size_t)node * 24 + 2 * c]     = w0;
    a14[(size_t)node * 24 + 2 * c + 1] = w1;
}

// ---------------------------------------------------------------------------
// GEMM1 (bf16 MFMA, persistent-W): h = relu(A1 @ W1t^T + b1), h bf16.
// Grid 512 blocks; each loops over 32-row tiles with W resident in LDS.
// ---------------------------------------------------------------------------
#define NT1 (MROWS / 32)
__global__ __launch_bounds__(256) void gemm1_mfma(
    const uint4* __restrict__ a14, const uint4* __restrict__ w4,
    const float* __restrict__ b1, unsigned short* __restrict__ h)
{
    constexpr int KD = 192, KP = KD + 8;          // padded bf16 stride (200)
    __shared__ unsigned short lw[128 * KP];       // 51200 B
    __shared__ unsigned short la[32 * KP];        // 12800 B
    int t = threadIdx.x;
    uint4* lw4 = (uint4*)lw;
    uint4* la4 = (uint4*)la;
    for (int i = t; i < 128 * 24; i += 256) {
        int r = i / 24, c = i - r * 24;
        lw4[r * 25 + c] = w4[i];
    }
    int wave = t >> 6, lane = t & 63;
    int m = lane & 15, half = lane >> 4;          // 0..3
    int koff = half * 8;
    int col0 = wave * 32 + m;
    int col1 = wave * 32 + 16 + m;
    float bias0 = b1[col0], bias1 = b1[col1];

    for (int tile = blockIdx.x; tile < NT1; tile += 512) {
        int row0 = tile * 32;
        __syncthreads();                           // prev readers done; lw ready
        for (int i = t; i < 32 * 24; i += 256) {
            int r = i / 24, c = i - r * 24;
            la4[r * 25 + c] = a14[(size_t)(row0 + r) * 24 + c];
        }
        __syncthreads();

        f32x4 acc00 = {}, acc01 = {}, acc10 = {}, acc11 = {};
#pragma unroll
        for (int k0 = 0; k0 < KD; k0 += 32) {
            short8 A0 = *(const short8*)&la[(m)      * KP + k0 + koff];
            short8 A1 = *(const short8*)&la[(16 + m) * KP + k0 + koff];
            short8 B0 = *(const short8*)&lw[(wave * 32 + m)      * KP + k0 + koff];
            short8 B1 = *(const short8*)&lw[(wave * 32 + 16 + m) * KP + k0 + koff];
            acc00 = __builtin_amdgcn_mfma_f32_16x16x32_bf16(A0, B0, acc00, 0, 0, 0);
            acc01 = __builtin_amdgcn_mfma_f32_16x16x32_bf16(A0, B1, acc01, 0, 0, 0);
            acc10 = __builtin_amdgcn_mfma_f32_16x16x32_bf16(A1, B0, acc10, 0, 0, 0);
            acc11 = __builtin_amdgcn_mfma_f32_16x16x32_bf16(A1, B1, acc11, 0, 0, 0);
        }
#pragma unroll
        for (int reg = 0; reg < 4; reg++) {
            int r0 = row0 + half * 4 + reg;
            int r1 = r0 + 16;
            if (r0 < N_NODES) {
                h[(size_t)r0 * 128 + col0] = (unsigned short)f2bf(fmaxf(acc00[reg] + bias0, 0.f));
                h[(size_t)r0 * 128 + col1] = (unsigned short)f2bf(fmaxf(acc01[reg] + bias1, 0.f));
            }
            if (r1 < N_NODES) {
                h[(size_t)r1 * 128 + col0] = (unsigned short)f2bf(fmaxf(acc10[reg] + bias0, 0.f));
                h[(size_t)r1 * 128 + col1] = (unsigned short)f2bf(fmaxf(acc11[reg] + bias1, 0.f));
            }
        }
    }
}

// ---------------------------------------------------------------------------
// GEMM2 (bf16 MFMA, persistent-W): [p|q] = h @ W2t^T; p bf16 (cols 0..63),
// q = +b2 -> out fp32 (cols 64..127).
// ---------------------------------------------------------------------------
__global__ __launch_bounds__(256) void gemm2_mfma(
    const uint4* __restrict__ h4, const uint4* __restrict__ w4,
    const float* __restrict__ b2, unsigned short* __restrict__ p,
    float* __restrict__ out)
{
    constexpr int KD = 128, KP = KD + 8;          // 136
    __shared__ unsigned short lw[128 * KP];       // 34816 B
    __shared__ unsigned short la[32 * KP];        // 8704 B
    int t = threadIdx.x;
    uint4* lw4 = (uint4*)lw;
    uint4* la4 = (uint4*)la;
    for (int i = t; i < 128 * 16; i += 256) {
        int r = i >> 4, c = i & 15;
        lw4[r * 17 + c] = w4[i];
    }
    int wave = t >> 6, lane = t & 63;
    int m = lane & 15, half = lane >> 4;
    int koff = half * 8;
    int col0 = wave * 32 + m;
    int col1 = wave * 32 + 16 + m;

    for (int tile = blockIdx.x; tile < NT1; tile += 512) {
        int row0 = tile * 32;
        __syncthreads();
        for (int i = t; i < 32 * 16; i += 256) {
            int r = i >> 4, c = i & 15;
            la4[r * 17 + c] = h4[(size_t)(row0 + r) * 16 + c];
        }
        __syncthreads();

        f32x4 acc00 = {}, acc01 = {}, acc10 = {}, acc11 = {};
#pragma unroll
        for (int k0 = 0; k0 < KD; k0 += 32) {
            short8 A0 = *(const short8*)&la[(m)      * KP + k0 + koff];
            short8 A1 = *(const short8*)&la[(16 + m) * KP + k0 + koff];
            short8 B0 = *(const short8*)&lw[(wave * 32 + m)      * KP + k0 + koff];
            short8 B1 = *(const short8*)&lw[(wave * 32 + 16 + m) * KP + k0 + koff];
            acc00 = __builtin_amdgcn_mfma_f32_16x16x32_bf16(A0, B0, acc00, 0, 0, 0);
            acc01 = __builtin_amdgcn_mfma_f32_16x16x32_bf16(A0, B1, acc01, 0, 0, 0);
            acc10 = __builtin_amdgcn_mfma_f32_16x16x32_bf16(A1, B0, acc10, 0, 0, 0);
            acc11 = __builtin_amdgcn_mfma_f32_16x16x32_bf16(A1, B1, acc11, 0, 0, 0);
        }
#pragma unroll
        for (int reg = 0; reg < 4; reg++) {
            int r0 = row0 + half * 4 + reg;
            int r1 = r0 + 16;
            float v00 = acc00[reg], v01 = acc01[reg];
            float v10 = acc10[reg], v11 = acc11[reg];
            if (r0 < N_NODES) {
                if (col0 < 64) p[(size_t)r0 * 64 + col0] = (unsigned short)f2bf(v00);
                else           out[(size_t)r0 * 64 + col0 - 64] = v00 + b2[col0 - 64];
                if (col1 < 64) p[(size_t)r0 * 64 + col1] = (unsigned short)f2bf(v01);
                else           out[(size_t)r0 * 64 + col1 - 64] = v01 + b2[col1 - 64];
            }
            if (r1 < N_NODES) {
                if (col0 < 64) p[(size_t)r1 * 64 + col0] = (unsigned short)f2bf(v10);
                else           out[(size_t)r1 * 64 + col0 - 64] = v10 + b2[col0 - 64];
                if (col1 < 64) p[(size_t)r1 * 64 + col1] = (unsigned short)f2bf(v11);
                else           out[(size_t)r1 * 64 + col1 - 64] = v11 + b2[col1 - 64];
            }
        }
    }
}

// ---------------------------------------------------------------------------
// Gather 2 + finalize: out[n] += (sum_{j in N(n)} p[j]) / deg(n)
// thread = (perm-pos, 32B chunk c in 0..3).
// ---------------------------------------------------------------------------
__global__ __launch_bounds__(256) void gather2_kernel(
    const int* __restrict__ perm, const int* __restrict__ rowstart,
    const int* __restrict__ cnt, const unsigned short* __restrict__ adj,
    const uint4* __restrict__ p4, float* __restrict__ out)
{
    int idx = blockIdx.x * 256 + threadIdx.x;
    if (idx >= N_NODES * 4) return;
    int i = idx >> 2;
    int c = idx & 3;
    int node = perm[i];
    int beg = rowstart[node];
    int d = cnt[node];
    int end = beg + d;
    float a0=0,a1=0,a2=0,a3=0,a4=0,a5=0,a6=0,a7=0;
    float b0=0,b1=0,b2=0,b3=0,b4=0,b5=0,b6=0,b7=0;
    for (int j = beg; j < end; j++) {
        int s = adj[j];
        uint4 u = p4[(size_t)s * 8 + 2 * c];
        uint4 v = p4[(size_t)s * 8 + 2 * c + 1];
        a0 += blo(u.x); a1 += bhi(u.x); a2 += blo(u.y); a3 += bhi(u.y);
        a4 += blo(u.z); a5 += bhi(u.z); a6 += blo(u.w); a7 += bhi(u.w);
        b0 += blo(v.x); b1 += bhi(v.x); b2 += blo(v.y); b3 += bhi(v.y);
        b4 += blo(v.z); b5 += bhi(v.z); b6 += blo(v.w); b7 += bhi(v.w);
    }
    float id = 1.0f / (float)max(d, 1);
    float4* o4 = (float4*)out;
    size_t base = (size_t)node * 16 + 4 * c;
    float4 u0 = o4[base], u1 = o4[base + 1], u2 = o4[base + 2], u3 = o4[base + 3];
    u0.x = fmaf(a0, id, u0.x); u0.y = fmaf(a1, id, u0.y);
    u0.z = fmaf(a2, id, u0.z); u0.w = fmaf(a3, id, u0.w);
    u1.x = fmaf(a4, id, u1.x); u1.y = fmaf(a5, id, u1.y);
    u1.z = fmaf(a6, id, u1.z); u1.w = fmaf(a7, id, u1.w);
    u2.x = fmaf(b0, id, u2.x); u2.y = fmaf(b1, id, u2.y);
    u2.z = fmaf(b2, id, u2.z); u2.w = fmaf(b3, id, u2.w);
    u3.x = fmaf(b4, id, u3.x); u3.y = fmaf(b5, id, u3.y);
    u3.z = fmaf(b6, id, u3.z); u3.w = fmaf(b7, id, u3.w);
    o4[base] = u0; o4[base + 1] = u1; o4[base + 2] = u2; o4[base + 3] = u3;
}

extern "C" void kernel_launch(void* const* d_in, const int* in_sizes, int n_in,
                              void* d_out, int out_size, void* d_ws, size_t ws_size,
                              hipStream_t stream)
{
    const float* x   = (const float*)d_in[0];
    const int*   ei  = (const int*)d_in[1];
    const float* w1l = (const float*)d_in[2];
    const float* w1r = (const float*)d_in[3];
    const float* b1  = (const float*)d_in[4];
    const float* w2l = (const float*)d_in[5];
    const float* w2r = (const float*)d_in[6];
    const float* b2  = (const float*)d_in[7];
    float* out = (float*)d_out;

    int E = in_sizes[1] / 2;                  // edge_index is [2, E]
    const int* src = ei;
    const int* dst = ei + E;

    // Workspace layout (4B units, arrays kept 16B-aligned).
    int* gh       = (int*)d_ws;                        // 39200
    int* ofs      = gh + NWG * NB;                     // 39200
    int* base     = ofs + NWG * NB;                    // 256
    int* cnt      = base + 256;                        // 50000
    int* rowstart = cnt + N_NODES;                     // 50000
    int* dh       = rowstart + N_NODES;                // 256
    int* dcur     = dh + 256;                          // 256
    int* perm     = dcur + 256;                        // 50000
    unsigned int* pairs = (unsigned int*)(perm + N_NODES);   // 800000 uint
    unsigned short* adj = (unsigned short*)(pairs + 800000); // 800000 u16
    unsigned short* xb  = adj + 800000;                // 50000*96 bf16
    unsigned short* A1  = xb + (size_t)N_NODES * IN_C; // 50016*192 bf16
    unsigned short* h   = A1 + (size_t)MROWS * 192;    // 50016*128 bf16
    unsigned short* p   = h  + (size_t)MROWS * 128;    // 50000*64 bf16
    unsigned short* Wt1 = p  + (size_t)N_NODES * 64;   // 128*192 bf16
    unsigned short* Wt2 = Wt1 + 128 * 192;             // 128*128 bf16

    hipMemsetAsync(dh, 0, 256 * sizeof(int), stream);

    // CSR build (locality-aware two-pass counting sort)
    parta_hist<<<NWG, 256, 0, stream>>>(dst, gh, E);
    parta_scan<<<1, 256, 0, stream>>>(gh, ofs, base);
    parta_scatter<<<NWG, 256, 0, stream>>>(src, dst, ofs, pairs, E);
    partb_csr<<<NB, 256, 0, stream>>>(pairs, base, rowstart, cnt, adj);

    // Degree-sorted permutation for divergence-free gathers
    deg_hist<<<(N_NODES + 255) / 256, 256, 0, stream>>>(cnt, dh);
    deg_scan<<<1, 256, 0, stream>>>(dh, dcur);
    deg_fill<<<(N_NODES + 255) / 256, 256, 0, stream>>>(cnt, dcur, perm);

    conv_x_kernel<<<(N_NODES * 12 + 255) / 256, 256, 0, stream>>>(
        x, (uint4*)xb, (uint4*)A1);
    conv_w_kernel<<<(128 * 192 + 128 * 128 + 255) / 256, 256, 0, stream>>>(
        w1l, w1r, w2l, w2r, Wt1, Wt2);

    gather1_kernel<<<(N_NODES * 6 + 255) / 256, 256, 0, stream>>>(
        perm, rowstart, cnt, adj, (const uint4*)xb, (uint4*)A1);

    gemm1_mfma<<<512, 256, 0, stream>>>(
        (const uint4*)A1, (const uint4*)Wt1, b1, h);
    gemm2_mfma<<<512, 256, 0, stream>>>(
        (const uint4*)h, (const uint4*)Wt2, b2, p, out);

    gather2_kernel<<<(N_NODES * 4 + 255) / 256, 256, 0, stream>>>(
        perm, rowstart, cnt, adj, (const uint4*)p, out);
}

// Round 6
// 236.515 us; speedup vs baseline: 2.0794x; 2.0794x over previous
//
#include <hip/hip_runtime.h>
#include <hip/hip_bf16.h>

#define N_NODES 50000
#define IN_C    96
#define HID_C   128
#define OUT_C   64
#define MROWS   50016 // 32-row-tile padded M

// CSR-build partition params
#define NB      200   // coarse buckets
#define BSZ     250   // nodes per bucket (200*250 = 50000)
#define WCHUNK  4096  // edges per workgroup in partition passes
#define NWG     196   // ceil(800000/4096)
#define DWG     196   // ceil(50000/256) node chunks for degree sort

typedef __attribute__((ext_vector_type(8))) short short8;  // 8 bf16 (4 VGPR)
typedef __attribute__((ext_vector_type(4))) float f32x4;

// round-to-nearest-even fp32 -> bf16 bits
__device__ inline unsigned int f2bf(float f) {
    unsigned int u = __float_as_uint(f);
    return (u + 0x7fffu + ((u >> 16) & 1u)) >> 16;
}
__device__ inline unsigned int pack2(float lo, float hi) {
    return f2bf(lo) | (f2bf(hi) << 16);
}
__device__ inline float blo(unsigned int u) { return __uint_as_float(u << 16); }
__device__ inline float bhi(unsigned int u) { return __uint_as_float(u & 0xffff0000u); }

// ---------------------------------------------------------------------------
// P1: per-WG coarse histogram (LDS, no global atomics).
// ---------------------------------------------------------------------------
__global__ __launch_bounds__(256) void parta_hist(
    const int* __restrict__ dst, int* __restrict__ gh, int E)
{
    __shared__ int h[NB];
    int t = threadIdx.x;
    if (t < NB) h[t] = 0;
    __syncthreads();
    int base_e = blockIdx.x * WCHUNK;
    for (int i = t; i < WCHUNK; i += 256) {
        int e = base_e + i;
        if (e < E) atomicAdd(&h[dst[e] / BSZ], 1);
    }
    __syncthreads();
    if (t < NB) gh[blockIdx.x * NB + t] = h[t];
}

// ---------------------------------------------------------------------------
// P2: bucket bases (exclusive scan of totals) + per-(WG,bucket) offsets.
// ---------------------------------------------------------------------------
__global__ __launch_bounds__(256) void parta_scan(
    const int* __restrict__ gh, int* __restrict__ ofs,
    int* __restrict__ base)
{
    __shared__ int buf[256];
    int t = threadIdx.x;
    int tot = 0;
    if (t < NB) {
        for (int w = 0; w < NWG; w++) tot += gh[w * NB + t];
    }
    buf[t] = tot;
    __syncthreads();
    for (int off = 1; off < 256; off <<= 1) {       // inclusive scan
        int v = (t >= off) ? buf[t - off] : 0;
        __syncthreads();
        buf[t] += v;
        __syncthreads();
    }
    if (t < NB) {
        int excl = buf[t] - tot;
        base[t] = excl;
        if (t == NB - 1) base[NB] = excl + tot;     // == E
        int run = excl;
        for (int w = 0; w < NWG; w++) {
            ofs[w * NB + t] = run;
            run += gh[w * NB + t];
        }
    }
}

// ---------------------------------------------------------------------------
// P3: partition edges into bucket-ordered packed records:
// rec = src (16b) | bucket-local dst (8b) << 16.  4 B/edge.
// ---------------------------------------------------------------------------
__global__ __launch_bounds__(256) void parta_scatter(
    const int* __restrict__ src, const int* __restrict__ dst,
    const int* __restrict__ ofs, unsigned int* __restrict__ pairs, int E)
{
    __shared__ int cur[NB];
    int t = threadIdx.x;
    if (t < NB) cur[t] = ofs[blockIdx.x * NB + t];
    __syncthreads();
    int base_e = blockIdx.x * WCHUNK;
    for (int i = t; i < WCHUNK; i += 256) {
        int e = base_e + i;
        if (e < E) {
            int d = dst[e];
            int b = d / BSZ;
            int pos = atomicAdd(&cur[b], 1);
            pairs[pos] = (unsigned)src[e] | ((unsigned)(d - b * BSZ) << 16);
        }
    }
}

// ---------------------------------------------------------------------------
// P4: per-bucket fine CSR (LDS hist + scan + rank); adj as ushort (src<65536).
// ---------------------------------------------------------------------------
__global__ __launch_bounds__(256) void partb_csr(
    const unsigned int* __restrict__ pairs, const int* __restrict__ base,
    int* __restrict__ rowstart, int* __restrict__ cnt,
    unsigned short* __restrict__ adj)
{
    __shared__ int h[256];
    __shared__ int buf[256];
    __shared__ int cur[256];
    int b = blockIdx.x;
    int t = threadIdx.x;
    int beg = base[b], end = base[b + 1];
    int node0 = b * BSZ;
    h[t] = 0;
    __syncthreads();
    for (int i = beg + t; i < end; i += 256)
        atomicAdd(&h[pairs[i] >> 16], 1);
    __syncthreads();
    int c = h[t];
    buf[t] = c;
    __syncthreads();
    for (int off = 1; off < 256; off <<= 1) {       // inclusive scan
        int v = (t >= off) ? buf[t - off] : 0;
        __syncthreads();
        buf[t] += v;
        __syncthreads();
    }
    int excl = buf[t] - c;
    if (t < BSZ) {
        rowstart[node0 + t] = beg + excl;
        cnt[node0 + t] = c;
    }
    cur[t] = beg + excl;
    __syncthreads();
    for (int i = beg + t; i < end; i += 256) {
        unsigned int pr = pairs[i];
        int pos = atomicAdd(&cur[pr >> 16], 1);
        adj[pos] = (unsigned short)(pr & 0xffffu);
    }
}

// ---------------------------------------------------------------------------
// Degree-sort (contention-free): per-WG LDS histogram -> scan -> LDS-cursor
// fill. All atomics in LDS; round-5's version hammered ~30 hot GLOBAL
// addresses and cost 267 us.
// ---------------------------------------------------------------------------
__global__ __launch_bounds__(256) void deg_hist(
    const int* __restrict__ cnt, int* __restrict__ gh2)
{
    __shared__ int h[256];
    int t = threadIdx.x;
    h[t] = 0;
    __syncthreads();
    int n = blockIdx.x * 256 + t;
    if (n < N_NODES) atomicAdd(&h[min(cnt[n], 255)], 1);
    __syncthreads();
    gh2[blockIdx.x * 256 + t] = h[t];
}

__global__ __launch_bounds__(256) void deg_scan(
    const int* __restrict__ gh2, int* __restrict__ ofs2)
{
    __shared__ int buf[256];
    int t = threadIdx.x;
    int tot = 0;
    for (int w = 0; w < DWG; w++) tot += gh2[w * 256 + t];
    buf[t] = tot;
    __syncthreads();
    for (int off = 1; off < 256; off <<= 1) {       // inclusive scan
        int v = (t >= off) ? buf[t - off] : 0;
        __syncthreads();
        buf[t] += v;
        __syncthreads();
    }
    int run = buf[t] - tot;                          // exclusive base of bin t
    for (int w = 0; w < DWG; w++) {
        ofs2[w * 256 + t] = run;
        run += gh2[w * 256 + t];
    }
}

__global__ __launch_bounds__(256) void deg_fill(
    const int* __restrict__ cnt, const int* __restrict__ ofs2,
    int* __restrict__ perm)
{
    __shared__ int cur[256];
    int t = threadIdx.x;
    cur[t] = ofs2[blockIdx.x * 256 + t];
    __syncthreads();
    int n = blockIdx.x * 256 + t;
    if (n < N_NODES) {
        int pos = atomicAdd(&cur[min(cnt[n], 255)], 1);
        perm[pos] = n;
    }
}

// ---------------------------------------------------------------------------
// Converters (fp32 -> bf16)
// ---------------------------------------------------------------------------
__global__ __launch_bounds__(256) void conv_x_kernel(
    const float* __restrict__ x, uint4* __restrict__ xb4,
    uint4* __restrict__ a14)
{
    int idx = blockIdx.x * 256 + threadIdx.x;     // N*12
    if (idx >= N_NODES * 12) return;
    int node = idx / 12;
    int c = idx - node * 12;
    const float4* x4 = (const float4*)x;
    float4 u = x4[(size_t)node * 24 + 2 * c];
    float4 v = x4[(size_t)node * 24 + 2 * c + 1];
    uint4 w;
    w.x = pack2(u.x, u.y); w.y = pack2(u.z, u.w);
    w.z = pack2(v.x, v.y); w.w = pack2(v.z, v.w);
    xb4[(size_t)node * 12 + c] = w;
    a14[(size_t)node * 24 + 12 + c] = w;
}

// Fused weight convert: W1t[128][192] and W2t[128][128].
__global__ __launch_bounds__(256) void conv_w_kernel(
    const float* __restrict__ w1l, const float* __restrict__ w1r,
    const float* __restrict__ w2l, const float* __restrict__ w2r,
    unsigned short* __restrict__ wt1, unsigned short* __restrict__ wt2)
{
    int i = blockIdx.x * 256 + threadIdx.x;
    if (i < 128 * 192) {
        int col = i / 192, k = i - col * 192;
        float v = (k < 96) ? w1l[k * 128 + col] : w1r[(k - 96) * 128 + col];
        wt1[i] = (unsigned short)f2bf(v);
    } else {
        int j = i - 128 * 192;
        if (j < 128 * 128) {
            int col = j / 128, k = j - col * 128;
            float v = (col < 64) ? w2l[k * 64 + col] : w2r[k * 64 + col - 64];
            wt2[j] = (unsigned short)f2bf(v);
        }
    }
}

// ---------------------------------------------------------------------------
// Gather 1: A1[n][0..95] = (sum_{j in N(n)} xb[j]) / deg(n), bf16 out.
// thread = (perm-pos, 32B chunk c in 0..5); 2 independent uint4 loads/edge.
// ---------------------------------------------------------------------------
__global__ __launch_bounds__(256) void gather1_kernel(
    const int* __restrict__ perm, const int* __restrict__ rowstart,
    const int* __restrict__ cnt, const unsigned short* __restrict__ adj,
    const uint4* __restrict__ xb4, uint4* __restrict__ a14)
{
    int idx = blockIdx.x * 256 + threadIdx.x;
    if (idx >= N_NODES * 6) return;
    int i = idx / 6;
    int c = idx - i * 6;
    int node = perm[i];
    int beg = rowstart[node];
    int d = cnt[node];
    int end = beg + d;
    float a0=0,a1=0,a2=0,a3=0,a4=0,a5=0,a6=0,a7=0;
    float b0=0,b1=0,b2=0,b3=0,b4=0,b5=0,b6=0,b7=0;
    for (int j = beg; j < end; j++) {
        int s = adj[j];
        uint4 u = xb4[(size_t)s * 12 + 2 * c];
        uint4 v = xb4[(size_t)s * 12 + 2 * c + 1];
        a0 += blo(u.x); a1 += bhi(u.x); a2 += blo(u.y); a3 += bhi(u.y);
        a4 += blo(u.z); a5 += bhi(u.z); a6 += blo(u.w); a7 += bhi(u.w);
        b0 += blo(v.x); b1 += bhi(v.x); b2 += blo(v.y); b3 += bhi(v.y);
        b4 += blo(v.z); b5 += bhi(v.z); b6 += blo(v.w); b7 += bhi(v.w);
    }
    float id = 1.0f / (float)max(d, 1);
    uint4 w0, w1;
    w0.x = pack2(a0 * id, a1 * id); w0.y = pack2(a2 * id, a3 * id);
    w0.z = pack2(a4 * id, a5 * id); w0.w = pack2(a6 * id, a7 * id);
    w1.x = pack2(b0 * id, b1 * id); w1.y = pack2(b2 * id, b3 * id);
    w1.z = pack2(b4 * id, b5 * id); w1.w = pack2(b6 * id, b7 * id);
    a14[(size_t)node * 24 + 2 * c]     = w0;
    a14[(size_t)node * 24 + 2 * c + 1] = w1;
}

// ---------------------------------------------------------------------------
// GEMM1 (bf16 MFMA, persistent-W): h = relu(A1 @ W1t^T + b1), h bf16.
// ---------------------------------------------------------------------------
#define NT1 (MROWS / 32)
__global__ __launch_bounds__(256) void gemm1_mfma(
    const uint4* __restrict__ a14, const uint4* __restrict__ w4,
    const float* __restrict__ b1, unsigned short* __restrict__ h)
{
    constexpr int KD = 192, KP = KD + 8;          // padded bf16 stride (200)
    __shared__ unsigned short lw[128 * KP];       // 51200 B
    __shared__ unsigned short la[32 * KP];        // 12800 B
    int t = threadIdx.x;
    uint4* lw4 = (uint4*)lw;
    uint4* la4 = (uint4*)la;
    for (int i = t; i < 128 * 24; i += 256) {
        int r = i / 24, c = i - r * 24;
        lw4[r * 25 + c] = w4[i];
    }
    int wave = t >> 6, lane = t & 63;
    int m = lane & 15, half = lane >> 4;          // 0..3
    int koff = half * 8;
    int col0 = wave * 32 + m;
    int col1 = wave * 32 + 16 + m;
    float bias0 = b1[col0], bias1 = b1[col1];

    for (int tile = blockIdx.x; tile < NT1; tile += 512) {
        int row0 = tile * 32;
        __syncthreads();                           // prev readers done; lw ready
        for (int i = t; i < 32 * 24; i += 256) {
            int r = i / 24, c = i - r * 24;
            la4[r * 25 + c] = a14[(size_t)(row0 + r) * 24 + c];
        }
        __syncthreads();

        f32x4 acc00 = {}, acc01 = {}, acc10 = {}, acc11 = {};
#pragma unroll
        for (int k0 = 0; k0 < KD; k0 += 32) {
            short8 A0 = *(const short8*)&la[(m)      * KP + k0 + koff];
            short8 A1 = *(const short8*)&la[(16 + m) * KP + k0 + koff];
            short8 B0 = *(const short8*)&lw[(wave * 32 + m)      * KP + k0 + koff];
            short8 B1 = *(const short8*)&lw[(wave * 32 + 16 + m) * KP + k0 + koff];
            acc00 = __builtin_amdgcn_mfma_f32_16x16x32_bf16(A0, B0, acc00, 0, 0, 0);
            acc01 = __builtin_amdgcn_mfma_f32_16x16x32_bf16(A0, B1, acc01, 0, 0, 0);
            acc10 = __builtin_amdgcn_mfma_f32_16x16x32_bf16(A1, B0, acc10, 0, 0, 0);
            acc11 = __builtin_amdgcn_mfma_f32_16x16x32_bf16(A1, B1, acc11, 0, 0, 0);
        }
#pragma unroll
        for (int reg = 0; reg < 4; reg++) {
            int r0 = row0 + half * 4 + reg;
            int r1 = r0 + 16;
            if (r0 < N_NODES) {
                h[(size_t)r0 * 128 + col0] = (unsigned short)f2bf(fmaxf(acc00[reg] + bias0, 0.f));
                h[(size_t)r0 * 128 + col1] = (unsigned short)f2bf(fmaxf(acc01[reg] + bias1, 0.f));
            }
            if (r1 < N_NODES) {
                h[(size_t)r1 * 128 + col0] = (unsigned short)f2bf(fmaxf(acc10[reg] + bias0, 0.f));
                h[(size_t)r1 * 128 + col1] = (unsigned short)f2bf(fmaxf(acc11[reg] + bias1, 0.f));
            }
        }
    }
}

// ---------------------------------------------------------------------------
// GEMM2 (bf16 MFMA, persistent-W): [p|q] = h @ W2t^T; p bf16 (cols 0..63),
// q = +b2 -> out fp32 (cols 64..127).
// ---------------------------------------------------------------------------
__global__ __launch_bounds__(256) void gemm2_mfma(
    const uint4* __restrict__ h4, const uint4* __restrict__ w4,
    const float* __restrict__ b2, unsigned short* __restrict__ p,
    float* __restrict__ out)
{
    constexpr int KD = 128, KP = KD + 8;          // 136
    __shared__ unsigned short lw[128 * KP];       // 34816 B
    __shared__ unsigned short la[32 * KP];        // 8704 B
    int t = threadIdx.x;
    uint4* lw4 = (uint4*)lw;
    uint4* la4 = (uint4*)la;
    for (int i = t; i < 128 * 16; i += 256) {
        int r = i >> 4, c = i & 15;
        lw4[r * 17 + c] = w4[i];
    }
    int wave = t >> 6, lane = t & 63;
    int m = lane & 15, half = lane >> 4;
    int koff = half * 8;
    int col0 = wave * 32 + m;
    int col1 = wave * 32 + 16 + m;

    for (int tile = blockIdx.x; tile < NT1; tile += 512) {
        int row0 = tile * 32;
        __syncthreads();
        for (int i = t; i < 32 * 16; i += 256) {
            int r = i >> 4, c = i & 15;
            la4[r * 17 + c] = h4[(size_t)(row0 + r) * 16 + c];
        }
        __syncthreads();

        f32x4 acc00 = {}, acc01 = {}, acc10 = {}, acc11 = {};
#pragma unroll
        for (int k0 = 0; k0 < KD; k0 += 32) {
            short8 A0 = *(const short8*)&la[(m)      * KP + k0 + koff];
            short8 A1 = *(const short8*)&la[(16 + m) * KP + k0 + koff];
            short8 B0 = *(const short8*)&lw[(wave * 32 + m)      * KP + k0 + koff];
            short8 B1 = *(const short8*)&lw[(wave * 32 + 16 + m) * KP + k0 + koff];
            acc00 = __builtin_amdgcn_mfma_f32_16x16x32_bf16(A0, B0, acc00, 0, 0, 0);
            acc01 = __builtin_amdgcn_mfma_f32_16x16x32_bf16(A0, B1, acc01, 0, 0, 0);
            acc10 = __builtin_amdgcn_mfma_f32_16x16x32_bf16(A1, B0, acc10, 0, 0, 0);
            acc11 = __builtin_amdgcn_mfma_f32_16x16x32_bf16(A1, B1, acc11, 0, 0, 0);
        }
#pragma unroll
        for (int reg = 0; reg < 4; reg++) {
            int r0 = row0 + half * 4 + reg;
            int r1 = r0 + 16;
            float v00 = acc00[reg], v01 = acc01[reg];
            float v10 = acc10[reg], v11 = acc11[reg];
            if (r0 < N_NODES) {
                if (col0 < 64) p[(size_t)r0 * 64 + col0] = (unsigned short)f2bf(v00);
                else           out[(size_t)r0 * 64 + col0 - 64] = v00 + b2[col0 - 64];
                if (col1 < 64) p[(size_t)r0 * 64 + col1] = (unsigned short)f2bf(v01);
                else           out[(size_t)r0 * 64 + col1 - 64] = v01 + b2[col1 - 64];
            }
            if (r1 < N_NODES) {
                if (col0 < 64) p[(size_t)r1 * 64 + col0] = (unsigned short)f2bf(v10);
                else           out[(size_t)r1 * 64 + col0 - 64] = v10 + b2[col0 - 64];
                if (col1 < 64) p[(size_t)r1 * 64 + col1] = (unsigned short)f2bf(v11);
                else           out[(size_t)r1 * 64 + col1 - 64] = v11 + b2[col1 - 64];
            }
        }
    }
}

// ---------------------------------------------------------------------------
// Gather 2 + finalize: out[n] += (sum_{j in N(n)} p[j]) / deg(n)
// thread = (perm-pos, 32B chunk c in 0..3).
// ---------------------------------------------------------------------------
__global__ __launch_bounds__(256) void gather2_kernel(
    const int* __restrict__ perm, const int* __restrict__ rowstart,
    const int* __restrict__ cnt, const unsigned short* __restrict__ adj,
    const uint4* __restrict__ p4, float* __restrict__ out)
{
    int idx = blockIdx.x * 256 + threadIdx.x;
    if (idx >= N_NODES * 4) return;
    int i = idx >> 2;
    int c = idx & 3;
    int node = perm[i];
    int beg = rowstart[node];
    int d = cnt[node];
    int end = beg + d;
    float a0=0,a1=0,a2=0,a3=0,a4=0,a5=0,a6=0,a7=0;
    float b0=0,b1=0,b2=0,b3=0,b4=0,b5=0,b6=0,b7=0;
    for (int j = beg; j < end; j++) {
        int s = adj[j];
        uint4 u = p4[(size_t)s * 8 + 2 * c];
        uint4 v = p4[(size_t)s * 8 + 2 * c + 1];
        a0 += blo(u.x); a1 += bhi(u.x); a2 += blo(u.y); a3 += bhi(u.y);
        a4 += blo(u.z); a5 += bhi(u.z); a6 += blo(u.w); a7 += bhi(u.w);
        b0 += blo(v.x); b1 += bhi(v.x); b2 += blo(v.y); b3 += bhi(v.y);
        b4 += blo(v.z); b5 += bhi(v.z); b6 += blo(v.w); b7 += bhi(v.w);
    }
    float id = 1.0f / (float)max(d, 1);
    float4* o4 = (float4*)out;
    size_t base = (size_t)node * 16 + 4 * c;
    float4 u0 = o4[base], u1 = o4[base + 1], u2 = o4[base + 2], u3 = o4[base + 3];
    u0.x = fmaf(a0, id, u0.x); u0.y = fmaf(a1, id, u0.y);
    u0.z = fmaf(a2, id, u0.z); u0.w = fmaf(a3, id, u0.w);
    u1.x = fmaf(a4, id, u1.x); u1.y = fmaf(a5, id, u1.y);
    u1.z = fmaf(a6, id, u1.z); u1.w = fmaf(a7, id, u1.w);
    u2.x = fmaf(b0, id, u2.x); u2.y = fmaf(b1, id, u2.y);
    u2.z = fmaf(b2, id, u2.z); u2.w = fmaf(b3, id, u2.w);
    u3.x = fmaf(b4, id, u3.x); u3.y = fmaf(b5, id, u3.y);
    u3.z = fmaf(b6, id, u3.z); u3.w = fmaf(b7, id, u3.w);
    o4[base] = u0; o4[base + 1] = u1; o4[base + 2] = u2; o4[base + 3] = u3;
}

extern "C" void kernel_launch(void* const* d_in, const int* in_sizes, int n_in,
                              void* d_out, int out_size, void* d_ws, size_t ws_size,
                              hipStream_t stream)
{
    const float* x   = (const float*)d_in[0];
    const int*   ei  = (const int*)d_in[1];
    const float* w1l = (const float*)d_in[2];
    const float* w1r = (const float*)d_in[3];
    const float* b1  = (const float*)d_in[4];
    const float* w2l = (const float*)d_in[5];
    const float* w2r = (const float*)d_in[6];
    const float* b2  = (const float*)d_in[7];
    float* out = (float*)d_out;

    int E = in_sizes[1] / 2;                  // edge_index is [2, E]
    const int* src = ei;
    const int* dst = ei + E;

    // Workspace layout (4B units, arrays kept 16B-aligned).
    int* gh       = (int*)d_ws;                        // 39200
    int* ofs      = gh + NWG * NB;                     // 39200
    int* base     = ofs + NWG * NB;                    // 256
    int* cnt      = base + 256;                        // 50000
    int* rowstart = cnt + N_NODES;                     // 50000
    int* gh2      = rowstart + N_NODES;                // 196*256 = 50176
    int* ofs2     = gh2 + DWG * 256;                   // 50176
    int* perm     = ofs2 + DWG * 256;                  // 50000
    unsigned int* pairs = (unsigned int*)(perm + N_NODES);   // 800000 uint
    unsigned short* adj = (unsigned short*)(pairs + 800000); // 800000 u16
    unsigned short* xb  = adj + 800000;                // 50000*96 bf16
    unsigned short* A1  = xb + (size_t)N_NODES * IN_C; // 50016*192 bf16
    unsigned short* h   = A1 + (size_t)MROWS * 192;    // 50016*128 bf16
    unsigned short* p   = h  + (size_t)MROWS * 128;    // 50000*64 bf16
    unsigned short* Wt1 = p  + (size_t)N_NODES * 64;   // 128*192 bf16
    unsigned short* Wt2 = Wt1 + 128 * 192;             // 128*128 bf16

    // CSR build (locality-aware two-pass counting sort)
    parta_hist<<<NWG, 256, 0, stream>>>(dst, gh, E);
    parta_scan<<<1, 256, 0, stream>>>(gh, ofs, base);
    parta_scatter<<<NWG, 256, 0, stream>>>(src, dst, ofs, pairs, E);
    partb_csr<<<NB, 256, 0, stream>>>(pairs, base, rowstart, cnt, adj);

    // Degree-sorted permutation (contention-free LDS-histogram version)
    deg_hist<<<DWG, 256, 0, stream>>>(cnt, gh2);
    deg_scan<<<1, 256, 0, stream>>>(gh2, ofs2);
    deg_fill<<<DWG, 256, 0, stream>>>(cnt, ofs2, perm);

    conv_x_kernel<<<(N_NODES * 12 + 255) / 256, 256, 0, stream>>>(
        x, (uint4*)xb, (uint4*)A1);
    conv_w_kernel<<<(128 * 192 + 128 * 128 + 255) / 256, 256, 0, stream>>>(
        w1l, w1r, w2l, w2r, Wt1, Wt2);

    gather1_kernel<<<(N_NODES * 6 + 255) / 256, 256, 0, stream>>>(
        perm, rowstart, cnt, adj, (const uint4*)xb, (uint4*)A1);

    gemm1_mfma<<<512, 256, 0, stream>>>(
        (const uint4*)A1, (const uint4*)Wt1, b1, h);
    gemm2_mfma<<<512, 256, 0, stream>>>(
        (const uint4*)h, (const uint4*)Wt2, b2, p, out);

    gather2_kernel<<<(N_NODES * 4 + 255) / 256, 256, 0, stream>>>(
        perm, rowstart, cnt, adj, (const uint4*)p, out);
}